// Round 4
// baseline (469.852 us; speedup 1.0000x reference)
//
#include <hip/hip_runtime.h>
#include <hip/hip_bf16.h>
#include <math.h>

#define N_TOKENS 16384
#define D_MODEL  4096
#define N_EXP    64

#define BK     16            // k-depth per LDS tile
#define XS_LD  260           // 256 tokens + 4 pad
#define PB_BLOCKS 512        // phaseB grid

// ---------------------------------------------------------------------------
// Transpose gate_w [64][4096] -> wt [4096][64] so that at fixed k the 64
// expert weights are contiguous (wave-uniform 64B chunks -> s_load).
// ---------------------------------------------------------------------------
__global__ void router_transpose(const float* __restrict__ w,
                                 float* __restrict__ wt) {
    int idx = blockIdx.x * 256 + threadIdx.x;
    int e = idx >> 12;
    int d = idx & 4095;
    wt[d * N_EXP + e] = w[idx];
}

// ---------------------------------------------------------------------------
// GEMM v4: block = 256 threads = 4 waves, tile = 256 tokens x 64 experts.
// Wave o owns experts [16o,16o+16) -> w addresses are wave-uniform -> the
// weights ride the SCALAR pipe (s_load_dwordx4/x16), FMAs use SGPR operand.
// Thread = 4 tokens x 16 experts (acc[4][16] = 64 VGPRs).
// Per k-step/thread: 1 ds_read_b128 (x) -> 64 v_fmac_f32. LDS pipe now ~2.7x
// under VALU demand (was 1.5x OVER in gemm3) -> VALU-bound.
// x staged transposed in LDS: xs[k][token], stores 2-way bank-aliased (free),
// reads contiguous 1024B (conflict-free).
// ---------------------------------------------------------------------------
__global__ void __launch_bounds__(256)
router_gemm4(const float* __restrict__ x, const float* __restrict__ wt,
             float* __restrict__ partial, int kslice) {
    __shared__ float xs[BK * XS_LD];   // 16.6 KB

    int tid  = threadIdx.x;
    int tok0 = blockIdx.x * 256;
    int k0   = blockIdx.y * kslice;

    int lane = tid & 63;
    int e0   = __builtin_amdgcn_readfirstlane((tid >> 6) * 16);
    int t0   = lane * 4;               // this thread's 4 tokens (in-block)

    // staging decomposition: thread covers token s_sub (+p*64), k-chunk s_kc
    int s_sub = tid >> 2;              // 0..63
    int s_kc  = (tid & 3) * 4;         // 0,4,8,12

    float acc[4][16];
#pragma unroll
    for (int t = 0; t < 4; ++t)
#pragma unroll
        for (int j = 0; j < 16; ++j) acc[t][j] = 0.f;

    for (int kk = 0; kk < kslice; kk += BK) {
        const float* xsrc = x + (size_t)tok0 * D_MODEL + k0 + kk;
        float4 xv0 = *(const float4*)(xsrc + (size_t)(s_sub +   0) * D_MODEL + s_kc);
        float4 xv1 = *(const float4*)(xsrc + (size_t)(s_sub +  64) * D_MODEL + s_kc);
        float4 xv2 = *(const float4*)(xsrc + (size_t)(s_sub + 128) * D_MODEL + s_kc);
        float4 xv3 = *(const float4*)(xsrc + (size_t)(s_sub + 192) * D_MODEL + s_kc);

        __syncthreads();   // previous tile's reads done

        xs[(s_kc + 0) * XS_LD + s_sub +   0] = xv0.x;
        xs[(s_kc + 1) * XS_LD + s_sub +   0] = xv0.y;
        xs[(s_kc + 2) * XS_LD + s_sub +   0] = xv0.z;
        xs[(s_kc + 3) * XS_LD + s_sub +   0] = xv0.w;
        xs[(s_kc + 0) * XS_LD + s_sub +  64] = xv1.x;
        xs[(s_kc + 1) * XS_LD + s_sub +  64] = xv1.y;
        xs[(s_kc + 2) * XS_LD + s_sub +  64] = xv1.z;
        xs[(s_kc + 3) * XS_LD + s_sub +  64] = xv1.w;
        xs[(s_kc + 0) * XS_LD + s_sub + 128] = xv2.x;
        xs[(s_kc + 1) * XS_LD + s_sub + 128] = xv2.y;
        xs[(s_kc + 2) * XS_LD + s_sub + 128] = xv2.z;
        xs[(s_kc + 3) * XS_LD + s_sub + 128] = xv2.w;
        xs[(s_kc + 0) * XS_LD + s_sub + 192] = xv3.x;
        xs[(s_kc + 1) * XS_LD + s_sub + 192] = xv3.y;
        xs[(s_kc + 2) * XS_LD + s_sub + 192] = xv3.z;
        xs[(s_kc + 3) * XS_LD + s_sub + 192] = xv3.w;

        __syncthreads();

        // wave-uniform weight rows for this tile
        const float* wrow = wt + (size_t)(k0 + kk) * N_EXP + e0;

#pragma unroll
        for (int k = 0; k < BK; ++k) {
            float4 xa = *(const float4*)&xs[k * XS_LD + t0];
            const float* wr = wrow + k * N_EXP;     // uniform address
#pragma unroll
            for (int j = 0; j < 16; ++j) {
                float wv = wr[j];                   // -> SGPR
                acc[0][j] = fmaf(xa.x, wv, acc[0][j]);
                acc[1][j] = fmaf(xa.y, wv, acc[1][j]);
                acc[2][j] = fmaf(xa.z, wv, acc[2][j]);
                acc[3][j] = fmaf(xa.w, wv, acc[3][j]);
            }
        }
    }

    // partial[slice][token][expert]; thread: tokens t0..t0+3, experts e0..+15
    float* po = partial + (size_t)blockIdx.y * (N_TOKENS * N_EXP)
                        + (size_t)(tok0 + t0) * N_EXP + e0;
#pragma unroll
    for (int t = 0; t < 4; ++t)
#pragma unroll
        for (int j = 0; j < 16; j += 4)
            *(float4*)(po + (size_t)t * N_EXP + j) =
                make_float4(acc[t][j], acc[t][j+1], acc[t][j+2], acc[t][j+3]);
}

// ---------------------------------------------------------------------------
// Phase B: reduce k-slices -> logits, softmax, top-2 (on logits; monotonic),
// write outputs + per-block p/f sums (no atomics).
// ---------------------------------------------------------------------------
__global__ void __launch_bounds__(256)
router_phaseB(const float* __restrict__ partial, int n_slices,
              float* __restrict__ out, float* __restrict__ block_sums) {
    __shared__ float p_acc[4][N_EXP];
    __shared__ float f_acc[4][N_EXP];

    int tid  = threadIdx.x;
    int wave = tid >> 6;
    int lane = tid & 63;

    p_acc[wave][lane] = 0.f;
    f_acc[wave][lane] = 0.f;

    for (int it = 0; it < 8; ++it) {
        int token = blockIdx.x * 32 + it * 4 + wave;

        float logit = 0.f;
        size_t base = (size_t)token * N_EXP + lane;
        for (int s = 0; s < n_slices; ++s)
            logit += partial[(size_t)s * (N_TOKENS * N_EXP) + base];

        // max + argmax (ties -> lower index, matching jax.lax.top_k)
        float m = logit; int i1 = lane;
#pragma unroll
        for (int off = 1; off < 64; off <<= 1) {
            float ov = __shfl_xor(m, off, 64);
            int   oi = __shfl_xor(i1, off, 64);
            if (ov > m || (ov == m && oi < i1)) { m = ov; i1 = oi; }
        }

        float p = expf(logit - m);
        float denom = p;
#pragma unroll
        for (int off = 1; off < 64; off <<= 1)
            denom += __shfl_xor(denom, off, 64);

        p_acc[wave][lane] += p / denom;

        // 2nd max + argmax, excluding i1
        float l2 = (lane == i1) ? -__builtin_inff() : logit;
        int i2 = lane;
#pragma unroll
        for (int off = 1; off < 64; off <<= 1) {
            float ov = __shfl_xor(l2, off, 64);
            int   oi = __shfl_xor(i2, off, 64);
            if (ov > l2 || (ov == l2 && oi < i2)) { l2 = ov; i2 = oi; }
        }

        if (lane == i1) f_acc[wave][lane] += 1.f;

        if (lane == 0) {
            float p1 = 1.0f / denom;
            float p2 = expf(l2 - m) / denom;
            float s12 = p1 + p2;
            ((float2*)out)[token] = make_float2(p1 / s12, p2 / s12);
            ((float2*)(out + 2 * N_TOKENS))[token] =
                make_float2((float)i1, (float)i2);
        }
    }

    __syncthreads();
    if (tid < N_EXP) {
        float ps = p_acc[0][tid] + p_acc[1][tid] + p_acc[2][tid] + p_acc[3][tid];
        float fs = f_acc[0][tid] + f_acc[1][tid] + f_acc[2][tid] + f_acc[3][tid];
        block_sums[(size_t)blockIdx.x * 128 + tid]      = ps;
        block_sums[(size_t)blockIdx.x * 128 + 64 + tid] = fs;
    }
}

// ---------------------------------------------------------------------------
// Final: reduce block_sums, loss = 0.01 * sum_e (f_e/N)*(p_e/N).
// ---------------------------------------------------------------------------
__global__ void __launch_bounds__(256)
router_final(const float* __restrict__ block_sums, float* __restrict__ out) {
    __shared__ float sp[4][N_EXP];
    __shared__ float sf[4][N_EXP];

    int tid  = threadIdx.x;
    int wave = tid >> 6;
    int lane = tid & 63;

    float ps = 0.f, fs = 0.f;
    for (int b = wave * (PB_BLOCKS / 4); b < (wave + 1) * (PB_BLOCKS / 4); ++b) {
        ps += block_sums[(size_t)b * 128 + lane];
        fs += block_sums[(size_t)b * 128 + 64 + lane];
    }
    sp[wave][lane] = ps;
    sf[wave][lane] = fs;
    __syncthreads();

    if (tid < N_EXP) {
        float pt = sp[0][tid] + sp[1][tid] + sp[2][tid] + sp[3][tid];
        float ft = sf[0][tid] + sf[1][tid] + sf[2][tid] + sf[3][tid];
        float v = pt * ft;
#pragma unroll
        for (int off = 1; off < 64; off <<= 1)
            v += __shfl_xor(v, off, 64);
        if (tid == 0)
            out[4 * N_TOKENS] = 0.01f * v / ((float)N_TOKENS * (float)N_TOKENS);
    }
}

// ---------------------------------------------------------------------------
extern "C" void kernel_launch(void* const* d_in, const int* in_sizes, int n_in,
                              void* d_out, int out_size, void* d_ws, size_t ws_size,
                              hipStream_t stream) {
    const float* x = (const float*)d_in[0];
    const float* w = (const float*)d_in[1];
    float* out = (float*)d_out;
    char* ws = (char*)d_ws;

    const size_t WT_BYTES = (size_t)D_MODEL * N_EXP * sizeof(float);     // 1 MB
    const size_t BS_BYTES = (size_t)PB_BLOCKS * 128 * sizeof(float);     // 256 KB

    int ksplit = 1;
    for (int c = 16; c >= 1; c >>= 1) {
        size_t need = (size_t)c * N_TOKENS * N_EXP * sizeof(float)
                      + WT_BYTES + BS_BYTES + 512;
        if (need <= ws_size) { ksplit = c; break; }
    }

    size_t partial_bytes = (size_t)ksplit * N_TOKENS * N_EXP * sizeof(float);
    float* partial = (float*)ws;
    float* wt = (float*)(ws + partial_bytes);
    float* block_sums = (float*)(ws + partial_bytes + WT_BYTES);

    router_transpose<<<(N_EXP * D_MODEL) / 256, 256, 0, stream>>>(w, wt);

    dim3 gridA(N_TOKENS / 256, ksplit);
    router_gemm4<<<gridA, 256, 0, stream>>>(x, wt, partial, D_MODEL / ksplit);

    router_phaseB<<<PB_BLOCKS, 256, 0, stream>>>(partial, ksplit, out, block_sums);

    router_final<<<1, 256, 0, stream>>>(block_sums, out);
}